// Round 4
// baseline (63.910 us; speedup 1.0000x reference)
//
#include <hip/hip_runtime.h>

namespace {
constexpr int GH  = 48;
constexpr int GW  = 64;
constexpr int GHW = GH * GW;   // 3072
constexpr int NW  = 4;         // waves per block
constexpr int NT  = NW * 64;   // 256 threads
constexpr int RPW = GH / NW;   // 12 rows per wave
constexpr int NITER = 18;      // absmax evidence (R3): don't trim below ~16
}

// One block per (batch, channel). Chebyshev semi-iteration on
// L = I + weighted 5-pt Laplacian, spectrum in [1,9] (Gershgorin).
// lane = column; wave w owns rows 12w..12w+11 in registers.
// Horizontal neighbors via wave shuffle; vertical via registers except the
// two strip-boundary rows, exchanged through double-buffered LDS (4 KB).
__global__ __launch_bounds__(NT)
void gridsmoother_cheb(const float* __restrict__ ae,
                       const float* __restrict__ wxwy,
                       float* __restrict__ out)
{
    const int bc = blockIdx.x;      // batch*16 + channel
    const int b  = bc >> 4;
    const int t  = threadIdx.x;
    const int w  = t >> 6;          // wave 0..3
    const int ln = t & 63;          // column 0..63
    const int r0 = w * RPW;         // first row of this wave's strip

    const float* __restrict__ bvec = ae   + (size_t)bc * GHW;
    const float* __restrict__ gwx  = wxwy + (size_t)b * 2 * GHW;  // wx[b]
    const float* __restrict__ gwy  = gwx + GHW;                   // wy[b]

    __shared__ float s_bnd[2][2][NW][GW];   // [buf][top=0/bot=1][wave][col]

    float x[RPW], r[RPW], d[RPW], dg[RPW];
    float wl[RPW], wrt[RPW], wu[RPW], wdn[RPW];

    constexpr float theta  = 5.0f;           // (1+9)/2
    constexpr float delta  = 4.0f;           // (9-1)/2
    constexpr float sigma1 = theta / delta;  // 1.25, contraction 0.5/iter

    #pragma unroll
    for (int j = 0; j < RPW; ++j) {
        const int row = r0 + j;
        const float wxv = gwx[row * GW + ln];     // coalesced
        const float wyv = gwy[row * GW + ln];
        wrt[j] = (ln < GW - 1) ? wxv : 0.0f;      // edge (row,ln)-(row,ln+1)
        const float wlv = __shfl_up(wxv, 1, 64);  // wx[row, ln-1]
        wl[j]  = (ln > 0) ? wlv : 0.0f;
        wdn[j] = (row < GH - 1) ? wyv : 0.0f;     // edge (row,ln)-(row+1,ln)
        wu[j]  = (row > 0) ? gwy[(row - 1) * GW + ln] : 0.0f;
        dg[j]  = 1.0f + wl[j] + wrt[j] + wu[j] + wdn[j];
        const float bv = bvec[row * GW + ln];
        x[j] = 0.0f;
        r[j] = bv;                      // r0 = b
        d[j] = bv * (1.0f / theta);     // d0 = b / theta
    }
    // Publish strip-boundary rows of d to buffer 0.
    s_bnd[0][0][w][ln] = d[0];
    s_bnd[0][1][w][ln] = d[RPW - 1];
    __syncthreads();

    const int wm = (w > 0)      ? w - 1 : 0;       // clamped: wu==0 masks
    const int wp = (w < NW - 1) ? w + 1 : NW - 1;  // clamped: wdn==0 masks

    float rho = 1.0f / sigma1;   // 0.8
    int cur = 0;

    #pragma unroll 1
    for (int it = 0; it < NITER; ++it) {
        // Cross-wave vertical neighbors (published before last barrier).
        const float dup = s_bnd[cur][1][wm][ln];   // row r0-1
        const float ddn = s_bnd[cur][0][wp][ln];   // row r0+RPW
        float ad[RPW];
        #pragma unroll
        for (int j = 0; j < RPW; ++j) {
            const float sL = __shfl_up(d[j], 1, 64);    // col ln-1 (wl=0 @ln=0)
            const float sR = __shfl_down(d[j], 1, 64);  // col ln+1 (wrt=0 @63)
            const float up = (j == 0)       ? dup : d[j - 1];
            const float dn = (j == RPW - 1) ? ddn : d[j + 1];
            ad[j] = dg[j] * d[j] - wl[j] * sL - wrt[j] * sR
                  - wu[j] * up - wdn[j] * dn;
        }
        const float rho_new = 1.0f / (2.0f * sigma1 - rho);
        const float c1 = rho_new * rho;
        const float c2 = 2.0f * rho_new / delta;
        #pragma unroll
        for (int j = 0; j < RPW; ++j) {
            x[j] += d[j];
            r[j] -= ad[j];
            d[j]  = c1 * d[j] + c2 * r[j];
        }
        // Publish new boundary rows to the other buffer; one barrier/iter.
        s_bnd[cur ^ 1][0][w][ln] = d[0];
        s_bnd[cur ^ 1][1][w][ln] = d[RPW - 1];
        rho = rho_new;
        cur ^= 1;
        __syncthreads();
    }

    float* __restrict__ ob = out + (size_t)bc * GHW;
    #pragma unroll
    for (int j = 0; j < RPW; ++j) {
        ob[(r0 + j) * GW + ln] = x[j];   // coalesced per row
    }
}

extern "C" void kernel_launch(void* const* d_in, const int* in_sizes, int n_in,
                              void* d_out, int out_size, void* d_ws, size_t ws_size,
                              hipStream_t stream) {
    const float* ae   = (const float*)d_in[0];   // (4,16,48,64) f32
    const float* wxwy = (const float*)d_in[1];   // (4,2,48,64) f32
    float* out = (float*)d_out;                  // (4,16,48,64) f32
    hipLaunchKernelGGL(gridsmoother_cheb, dim3(64), dim3(NT), 0, stream,
                       ae, wxwy, out);
}